// Round 12
// baseline (297.031 us; speedup 1.0000x reference)
//
#include <hip/hip_runtime.h>

#define N_  64
#define CI  256
#define CO  256
#define CR  32
#define T_  64
#define V_  25
#define TV  (T_*V_)   // 1600
#define VV  (V_*V_)   // 625
#define ATS 640       // attnT per-(n,o) stride in shorts (625 used, pad to 16B-aligned)

typedef __attribute__((ext_vector_type(8))) short bshort8;
typedef __attribute__((ext_vector_type(4))) float f32x4;

__device__ inline unsigned short f2bf(float f) {
    unsigned int u = __float_as_uint(f);
    return (unsigned short)((u + 0x7FFFu + ((u >> 16) & 1u)) >> 16);
}

// ---------------- K1: mean over t + partial x1/x2 + w3/w4 frag cvt ----------------
// blocks 0..1023: (n, c-slice of 16): compute xm slice in-register, then
//                 part1/part2[n][slice][r*25+v] = sum_{c in slice} w1/w2[r,c]*xm[c,v]
// blocks 1024..1055: w3f fragment cvt;  blocks 1056..1059: w4f fragment cvt
__global__ __launch_bounds__(256) void k_mean_cvt(const float* __restrict__ x,
                                                  const float* __restrict__ w3,
                                                  const float* __restrict__ w4,
                                                  const float* __restrict__ w1,
                                                  const float* __restrict__ w2,
                                                  unsigned short* __restrict__ w3f,
                                                  unsigned short* __restrict__ w4f,
                                                  float* __restrict__ part1,
                                                  float* __restrict__ part2) {
    int b = blockIdx.x;
    int tid = threadIdx.x;
    if (b < 1024) {
        __shared__ float L[16 * 400];          // 16 c-rows x 400 j (16 t-rows)
        int n = b >> 4, sl = b & 15, c0 = sl * 16;
        float a0 = 0.f, a1 = 0.f;
        for (int ch = 0; ch < 4; ++ch) {
            for (int i = 0; i < 7; ++i) {
                int task = i * 256 + tid;      // 1600 float4 loads, coalesced
                if (task < 1600) {
                    int c = task / 100, f4 = task % 100;
                    *(float4*)&L[c * 400 + f4 * 4] =
                        *(const float4*)(x + (size_t)(n * CI + c0 + c) * TV + ch * 400 + f4 * 4);
                }
            }
            __syncthreads();
            {
                int c = tid / 25, v = tid % 25;
                float s = 0.f;
                #pragma unroll
                for (int tl = 0; tl < 16; ++tl) s += L[c * 400 + tl * 25 + v];
                a0 += s;
            }
            if (tid < 144) {
                int oi = tid + 256;
                int c = oi / 25, v = oi % 25;
                float s = 0.f;
                #pragma unroll
                for (int tl = 0; tl < 16; ++tl) s += L[c * 400 + tl * 25 + v];
                a1 += s;
            }
            __syncthreads();
        }
        // xm slice -> LDS (index c*25+v == tid / tid+256 by construction)
        float* Lx = L;                          // 400 floats, L free after last barrier
        Lx[tid] = a0 * (1.f / T_);
        if (tid < 144) Lx[tid + 256] = a1 * (1.f / T_);
        __syncthreads();
        // partial x1/x2 over this c-slice: 800 outputs
        size_t pbase = ((size_t)n * 16 + sl) * 800;
        for (int idx = tid; idx < CR * V_; idx += 256) {
            int r = idx / V_, v = idx % V_;
            const float* wr1 = w1 + (size_t)r * CI + c0;
            const float* wr2 = w2 + (size_t)r * CI + c0;
            float s1 = 0.f, s2 = 0.f;
            #pragma unroll
            for (int c = 0; c < 16; ++c) {
                float xv = Lx[c * 25 + v];
                s1 += wr1[c] * xv;
                s2 += wr2[c] * xv;
            }
            part1[pbase + idx] = s1;
            part2[pbase + idx] = s2;
        }
    } else if (b < 1056) {
        int f = (b - 1024) * 256 + tid;        // 0..8191
        int lane = f & 63;
        int ks = (f >> 6) & 7;
        int ot = f >> 9;
        const float* src = w3 + (size_t)(ot * 16 + (lane & 15)) * CI + ks * 32 + (lane >> 4) * 8;
        bshort8 v;
        #pragma unroll
        for (int i = 0; i < 8; ++i) v[i] = (short)f2bf(src[i]);
        *(bshort8*)(w3f + (size_t)f * 8) = v;
    } else {
        int f = (b - 1056) * 256 + tid;        // 0..1023
        int lane = f & 63;
        int ot = f >> 6;
        const float* src = w4 + (size_t)(ot * 16 + (lane & 15)) * CR + (lane >> 4) * 8;
        bshort8 v;
        #pragma unroll
        for (int i = 0; i < 8; ++i) v[i] = (short)f2bf(src[i]);
        *(bshort8*)(w4f + (size_t)f * 8) = v;
    }
}

// ---------------- K3+K4 merged: gemm1 (1600 blocks) + attn (512 blocks) ------------------
// blocks 0..1599:      gemm1: x3_bf[n,o,j] = bf16(w3 @ x + b3), n = bb/25, j0 = (bb%25)*64
// blocks 1600..2111:   attn:  attnT per (n, uv-slice); x1/x2 reconstructed from partials
__global__ __launch_bounds__(256) void k_attn_gemm(const float* __restrict__ x,
                                                   const unsigned short* __restrict__ w3f,
                                                   const float* __restrict__ b3,
                                                   unsigned short* __restrict__ x3,
                                                   const float* __restrict__ part1,
                                                   const float* __restrict__ part2,
                                                   const float* __restrict__ b1,
                                                   const float* __restrict__ b2,
                                                   const unsigned short* __restrict__ w4f,
                                                   const float* __restrict__ b4,
                                                   const float* __restrict__ A,
                                                   const int* __restrict__ alpha_p,
                                                   unsigned short* __restrict__ attnT) {
    __shared__ __align__(16) unsigned char smem[65536];
    int tid = threadIdx.x;
    int bb  = blockIdx.x;
    if (bb < 1600) {
        // ---------------- gemm1 path ----------------
        unsigned short* sB = (unsigned short*)smem;   // [64 j][256 c] swizzled
        int n = bb / 25, j0 = (bb % 25) * 64;
        int lane = tid & 63, wave = tid >> 6;
        const float* gx = x + (size_t)n * CI * TV + j0;
        for (int i = 0; i < 16; ++i) {
            int task = i * 256 + tid;
            int c = task >> 4, chunk = task & 15;
            float4 v = *(const float4*)(gx + (size_t)c * TV + chunk * 4);
            int g0 = c >> 3, cl = c & 7;
            #pragma unroll
            for (int k = 0; k < 4; ++k) {
                int j = chunk * 4 + k;
                int f = g0 ^ (j & 7) ^ ((j >> 2) & 7);
                float val = (k == 0) ? v.x : (k == 1) ? v.y : (k == 2) ? v.z : v.w;
                sB[j * 256 + f * 8 + cl] = f2bf(val);
            }
        }
        __syncthreads();
        int quad = lane >> 4, c16 = lane & 15;
        const bshort8* Af = (const bshort8*)w3f;
        f32x4 acc[4][4];
        #pragma unroll
        for (int mt = 0; mt < 4; ++mt)
            #pragma unroll
            for (int nt = 0; nt < 4; ++nt) acc[mt][nt] = (f32x4){0,0,0,0};
        #pragma unroll
        for (int ks = 0; ks < 8; ++ks) {
            bshort8 b[4], a[4];
            #pragma unroll
            for (int nt = 0; nt < 4; ++nt) {
                int rB = nt * 16 + c16;
                int cidx = ks * 4 + quad;
                int f = cidx ^ (rB & 7) ^ ((rB >> 2) & 7);
                b[nt] = *(const bshort8*)(&sB[rB * 256 + f * 8]);
            }
            #pragma unroll
            for (int mt = 0; mt < 4; ++mt)
                a[mt] = Af[(size_t)(((wave * 4 + mt) * 8 + ks) * 64) + lane];
            #pragma unroll
            for (int mt = 0; mt < 4; ++mt)
                #pragma unroll
                for (int nt = 0; nt < 4; ++nt)
                    acc[mt][nt] = __builtin_amdgcn_mfma_f32_16x16x32_bf16(a[mt], b[nt], acc[mt][nt], 0, 0, 0);
        }
        __syncthreads();                      // sB free; alias as epilogue buffer
        unsigned short* eS = sB;              // 128 rows x stride 72 shorts
        #pragma unroll
        for (int pass = 0; pass < 2; ++pass) {
            if ((wave >> 1) == pass) {
                #pragma unroll
                for (int mt = 0; mt < 4; ++mt) {
                    int o = wave * 64 + mt * 16 + quad * 4;
                    float4 bvv = *(const float4*)(b3 + o);
                    int ol = (wave & 1) * 64 + mt * 16 + quad * 4;
                    #pragma unroll
                    for (int nt = 0; nt < 4; ++nt) {
                        int jc = nt * 16 + c16;
                        eS[(ol + 0) * 72 + jc] = f2bf(acc[mt][nt][0] + bvv.x);
                        eS[(ol + 1) * 72 + jc] = f2bf(acc[mt][nt][1] + bvv.y);
                        eS[(ol + 2) * 72 + jc] = f2bf(acc[mt][nt][2] + bvv.z);
                        eS[(ol + 3) * 72 + jc] = f2bf(acc[mt][nt][3] + bvv.w);
                    }
                }
            }
            __syncthreads();
            #pragma unroll
            for (int i = 0; i < 4; ++i) {
                int task = i * 256 + tid;         // 1024
                int orow = task >> 3, seg = task & 7;
                bshort8 vv = *(const bshort8*)&eS[orow * 72 + seg * 8];
                *(bshort8*)(x3 + (size_t)(n * CO + pass * 128 + orow) * TV + j0 + seg * 8) = vv;
            }
            __syncthreads();
        }
    } else {
        // ---------------- attn path ----------------
        float* s_x1 = (float*)smem;               // 800
        float* s_x2 = s_x1 + CR * V_;             // 800
        float* s_A  = s_x2 + CR * V_;             // 625
        int ib = bb - 1600;
        int n = ib >> 3, by = ib & 7;
        float alpha = (float)alpha_p[0];
        // reconstruct x1/x2 from 16 c-slice partials (+ bias)
        const float* pp1 = part1 + (size_t)n * 16 * 800;
        const float* pp2 = part2 + (size_t)n * 16 * 800;
        for (int i = tid; i < CR * V_; i += 256) {
            float s1 = b1[i / V_], s2 = b2[i / V_];
            #pragma unroll
            for (int s = 0; s < 16; ++s) {
                s1 += pp1[s * 800 + i];
                s2 += pp2[s * 800 + i];
            }
            s_x1[i] = s1;
            s_x2[i] = s2;
        }
        for (int i = tid; i < VV; i += 256) s_A[i] = A[i];
        __syncthreads();
        int wave = tid >> 6, lane = tid & 63;
        int task = by * 4 + wave;               // 0..31
        int og   = task & 3;
        int ug   = task >> 2;
        int o0   = og * 64;
        int quad = lane >> 4, c16 = lane & 15;
        bshort8 a[4];
        #pragma unroll
        for (int ot = 0; ot < 4; ++ot)
            a[ot] = *(const bshort8*)(w4f + (size_t)(((og * 4) + ot) * 64 + lane) * 8);
        float4 bv[4];
        #pragma unroll
        for (int ot = 0; ot < 4; ++ot)
            bv[ot] = *(const float4*)(b4 + o0 + ot * 16 + quad * 4);
        int r0 = quad * 8;
        #pragma unroll
        for (int it = 0; it < 5; ++it) {
            int uv0 = (ug * 5 + it) * 16;
            int uvc = uv0 + c16;
            bool valid = uvc < VV;
            int uvcc = valid ? uvc : (VV - 1);
            int u = uvcc % V_, v = uvcc / V_;
            bshort8 b;
            #pragma unroll
            for (int i = 0; i < 8; ++i) {
                float d = s_x1[(r0 + i) * V_ + u] - s_x2[(r0 + i) * V_ + v];
                b[i] = (short)f2bf(tanhf(d));
            }
            float Auv = s_A[u * V_ + v];
            f32x4 acc[4];
            #pragma unroll
            for (int ot = 0; ot < 4; ++ot)
                acc[ot] = __builtin_amdgcn_mfma_f32_16x16x32_bf16(a[ot], b, (f32x4){0,0,0,0}, 0, 0, 0);
            if (valid) {
                #pragma unroll
                for (int ot = 0; ot < 4; ++ot) {
                    #pragma unroll
                    for (int r = 0; r < 4; ++r) {
                        int o = o0 + ot * 16 + quad * 4 + r;
                        float bval = (r == 0) ? bv[ot].x : (r == 1) ? bv[ot].y
                                   : (r == 2) ? bv[ot].z : bv[ot].w;
                        attnT[(size_t)(n * CO + o) * ATS + uvc] =
                            f2bf((acc[ot][r] + bval) * alpha + Auv);
                    }
                }
            }
        }
    }
}

// ---------------- K5: MFMA contraction: out[t,v] = sum_u x3[t,u] * attnT[v,u] ----------------
// block = 4 (n,o) pairs, one wave each. A-frags gathered DIRECTLY from global x3
// (u-contiguous per frag; u>=25 lanes masked to 0). Only attnT staged to LDS (8KB).
__global__ __launch_bounds__(256) void k_contract(const unsigned short* __restrict__ x3,
                                                  const unsigned short* __restrict__ attnT,
                                                  float* __restrict__ out) {
    int no0 = blockIdx.x * 4;
    __shared__ __align__(16) unsigned short sB[4 * 1024];   // 4 x [32 v][32 u]
    int tid = threadIdx.x;
    int p = tid >> 6, lane = tid & 63;
    int quad = lane >> 4, c16 = lane & 15;
    const unsigned short* pAg = x3 + (size_t)(no0 + p) * TV;
    bshort8 a[4];
    #pragma unroll
    for (int mt = 0; mt < 4; ++mt) {
        int t = mt * 16 + c16;
        const unsigned short* rowp = pAg + t * 25 + quad * 8;
        bshort8 av;
        #pragma unroll
        for (int i = 0; i < 8; ++i) {
            unsigned short val = rowp[i];
            av[i] = (short)((quad * 8 + i < 25) ? val : (unsigned short)0);
        }
        a[mt] = av;
    }
    {
        int task = tid;                         // 4*25*7 = 700
        for (int i = 0; i < 3; ++i, task += 256)
            if (task < 700) {
                int pp = task / 175, rem = task % 175;
                sB[pp * 1024 + (rem / 7) * 32 + 25 + rem % 7] = 0;
            }
    }
    #pragma unroll
    for (int i = 0; i < 2; ++i) {
        int task = i * 256 + tid;              // 4*79 = 316
        if (task < 316) {
            int pp = task / 79, e8 = task % 79;
            bshort8 vv = *(const bshort8*)(attnT + (size_t)(no0 + pp) * ATS + e8 * 8);
            #pragma unroll
            for (int k = 0; k < 8; ++k) {
                int idx = e8 * 8 + k;
                if (idx < VV) {
                    int v = idx / 25, u = idx % 25;
                    sB[pp * 1024 + v * 32 + u] = (unsigned short)vv[k];
                }
            }
        }
    }
    __syncthreads();
    const unsigned short* pB = sB + p * 1024;
    bshort8 b[2];
    #pragma unroll
    for (int nt = 0; nt < 2; ++nt) b[nt] = *(const bshort8*)&pB[(nt * 16 + c16) * 32 + quad * 8];
    f32x4 acc[4][2];
    #pragma unroll
    for (int mt = 0; mt < 4; ++mt)
        #pragma unroll
        for (int nt = 0; nt < 2; ++nt)
            acc[mt][nt] = __builtin_amdgcn_mfma_f32_16x16x32_bf16(a[mt], b[nt], (f32x4){0,0,0,0}, 0, 0, 0);
    size_t ob = (size_t)(no0 + p) * TV;
    #pragma unroll
    for (int mt = 0; mt < 4; ++mt)
        #pragma unroll
        for (int nt = 0; nt < 2; ++nt) {
            int v = nt * 16 + c16;
            if (v < V_) {
                #pragma unroll
                for (int r = 0; r < 4; ++r) {
                    int t = mt * 16 + quad * 4 + r;
                    out[ob + t * 25 + v] = acc[mt][nt][r];
                }
            }
        }
}

extern "C" void kernel_launch(void* const* d_in, const int* in_sizes, int n_in,
                              void* d_out, int out_size, void* d_ws, size_t ws_size,
                              hipStream_t stream) {
    const float* x  = (const float*)d_in[0];
    const float* A  = (const float*)d_in[1];
    const float* w1 = (const float*)d_in[2];
    const float* b1 = (const float*)d_in[3];
    const float* w2 = (const float*)d_in[4];
    const float* b2 = (const float*)d_in[5];
    const float* w3 = (const float*)d_in[6];
    const float* b3 = (const float*)d_in[7];
    const float* w4 = (const float*)d_in[8];
    const float* b4 = (const float*)d_in[9];
    const int* alpha_p = (const int*)d_in[11];
    float* out = (float*)d_out;

    float* ws = (float*)d_ws;
    float* part1 = ws;                                         // 819200 f (64*16*800)
    float* part2 = ws + 819200;                                // 819200 f
    unsigned short* attnT = (unsigned short*)(ws + 1638400);   // 16384*640 us
    unsigned short* w3f   = attnT + (size_t)16384 * ATS;       // 65536 us
    unsigned short* w4f   = w3f + 65536;                       // 16384 us
    unsigned short* x3    = w4f + 16384;                       // 26214400 us

    k_mean_cvt<<<1060, 256, 0, stream>>>(x, w3, w4, w1, w2, w3f, w4f, part1, part2);
    k_attn_gemm<<<2112, 256, 0, stream>>>(x, w3f, b3, x3, part1, part2, b1, b2, w4f, b4, A, alpha_p, attnT);
    k_contract<<<4096, 256, 0, stream>>>(x3, attnT, out);
}

// Round 13
// 293.541 us; speedup vs baseline: 1.0119x; 1.0119x over previous
//
#include <hip/hip_runtime.h>

#define N_  64
#define CI  256
#define CO  256
#define CR  32
#define T_  64
#define V_  25
#define TV  (T_*V_)   // 1600
#define VV  (V_*V_)   // 625
#define ATS 640       // attnT per-(n,o) stride in shorts (625 used, pad to 16B-aligned)

typedef __attribute__((ext_vector_type(8))) short bshort8;
typedef __attribute__((ext_vector_type(4))) float f32x4;

__device__ inline unsigned short f2bf(float f) {
    unsigned int u = __float_as_uint(f);
    return (unsigned short)((u + 0x7FFFu + ((u >> 16) & 1u)) >> 16);
}

// ---------------- K1: mean over t (LDS-staged, coalesced) + w3/w4 frag cvt ----------------
// blocks 0..1023:    (n, c-group of 16): xm[n,c,v] = mean_t x[n,c,t,v]
// blocks 1024..1055: w3f[((ot*8+ks)*64+lane)*8+i] = w3[ot*16+(lane&15)][ks*32+(lane>>4)*8+i]
// blocks 1056..1059: w4f[(ot*64+lane)*8+i]        = w4[ot*16+(lane&15)][(lane>>4)*8+i]
__global__ __launch_bounds__(256) void k_mean_cvt(const float* __restrict__ x,
                                                  const float* __restrict__ w3,
                                                  const float* __restrict__ w4,
                                                  float* __restrict__ xm,
                                                  unsigned short* __restrict__ w3f,
                                                  unsigned short* __restrict__ w4f) {
    int b = blockIdx.x;
    int tid = threadIdx.x;
    if (b < 1024) {
        __shared__ float L[16 * 400];          // 16 c-rows x 400 j (16 t-rows)
        int n = b >> 4, c0 = (b & 15) * 16;
        float a0 = 0.f, a1 = 0.f;
        for (int ch = 0; ch < 4; ++ch) {
            for (int i = 0; i < 7; ++i) {
                int task = i * 256 + tid;      // 1600 float4 loads, coalesced
                if (task < 1600) {
                    int c = task / 100, f4 = task % 100;
                    *(float4*)&L[c * 400 + f4 * 4] =
                        *(const float4*)(x + (size_t)(n * CI + c0 + c) * TV + ch * 400 + f4 * 4);
                }
            }
            __syncthreads();
            {
                int c = tid / 25, v = tid % 25;
                float s = 0.f;
                #pragma unroll
                for (int tl = 0; tl < 16; ++tl) s += L[c * 400 + tl * 25 + v];
                a0 += s;
            }
            if (tid < 144) {
                int oi = tid + 256;
                int c = oi / 25, v = oi % 25;
                float s = 0.f;
                #pragma unroll
                for (int tl = 0; tl < 16; ++tl) s += L[c * 400 + tl * 25 + v];
                a1 += s;
            }
            __syncthreads();
        }
        xm[(size_t)(n * CI + c0) * V_ + tid] = a0 * (1.f / T_);
        if (tid < 144)
            xm[(size_t)(n * CI + c0) * V_ + tid + 256] = a1 * (1.f / T_);
    } else if (b < 1056) {
        int f = (b - 1024) * 256 + tid;        // 0..8191
        int lane = f & 63;
        int ks = (f >> 6) & 7;
        int ot = f >> 9;
        const float* src = w3 + (size_t)(ot * 16 + (lane & 15)) * CI + ks * 32 + (lane >> 4) * 8;
        bshort8 v;
        #pragma unroll
        for (int i = 0; i < 8; ++i) v[i] = (short)f2bf(src[i]);
        *(bshort8*)(w3f + (size_t)f * 8) = v;
    } else {
        int f = (b - 1056) * 256 + tid;        // 0..1023
        int lane = f & 63;
        int ot = f >> 6;
        const float* src = w4 + (size_t)(ot * 16 + (lane & 15)) * CR + (lane >> 4) * 8;
        bshort8 v;
        #pragma unroll
        for (int i = 0; i < 8; ++i) v[i] = (short)f2bf(src[i]);
        *(bshort8*)(w4f + (size_t)f * 8) = v;
    }
}

// ---------------- K2: x1/x2 = w1/w2 @ xm + b ; grid (n, 4) ----------------
__global__ __launch_bounds__(256) void k_x1x2(const float* __restrict__ xm,
                                              const float* __restrict__ w1,
                                              const float* __restrict__ b1,
                                              const float* __restrict__ w2,
                                              const float* __restrict__ b2,
                                              float* __restrict__ x1,
                                              float* __restrict__ x2) {
    int n = blockIdx.x, q = blockIdx.y;
    __shared__ float s_xm[CI * V_];
    const float4* src = (const float4*)(xm + (size_t)n * CI * V_);
    for (int i = threadIdx.x; i < CI * V_ / 4; i += 256) ((float4*)s_xm)[i] = src[i];
    __syncthreads();
    if (threadIdx.x < 200) {
        int idx = q * 200 + threadIdx.x;
        int r = idx / V_, v = idx % V_;
        const float* wr1 = w1 + (size_t)r * CI;
        const float* wr2 = w2 + (size_t)r * CI;
        float p1a = 0.f, p1b = 0.f, p2a = 0.f, p2b = 0.f;
        #pragma unroll 4
        for (int c = 0; c < CI; c += 2) {
            float xv0 = s_xm[c * V_ + v];
            float xv1 = s_xm[(c + 1) * V_ + v];
            p1a += wr1[c] * xv0;  p1b += wr1[c + 1] * xv1;
            p2a += wr2[c] * xv0;  p2b += wr2[c + 1] * xv1;
        }
        x1[n * CR * V_ + idx] = p1a + p1b + b1[r];
        x2[n * CR * V_ + idx] = p2a + p2b + b2[r];
    }
}

// ---------------- K3+K4 merged: gemm1 (1600 blocks) + attn (512 blocks) ------------------
// blocks 0..1599:      gemm1: x3_bf[n,o,j] = bf16(w3 @ x + b3), n = bb/25, j0 = (bb%25)*64
// blocks 1600..2111:   attn:  attnT per (n, uv-slice), n = b2>>3, by = b2&7
__global__ __launch_bounds__(256) void k_attn_gemm(const float* __restrict__ x,
                                                   const unsigned short* __restrict__ w3f,
                                                   const float* __restrict__ b3,
                                                   unsigned short* __restrict__ x3,
                                                   const float* __restrict__ x1,
                                                   const float* __restrict__ x2,
                                                   const unsigned short* __restrict__ w4f,
                                                   const float* __restrict__ b4,
                                                   const float* __restrict__ A,
                                                   const int* __restrict__ alpha_p,
                                                   unsigned short* __restrict__ attnT) {
    __shared__ __align__(16) unsigned char smem[65536];
    int tid = threadIdx.x;
    int bb  = blockIdx.x;
    if (bb < 1600) {
        // ---------------- gemm1 path ----------------
        unsigned short* sB = (unsigned short*)smem;   // [64 j][256 c] swizzled
        int n = bb / 25, j0 = (bb % 25) * 64;
        int lane = tid & 63, wave = tid >> 6;
        const float* gx = x + (size_t)n * CI * TV + j0;
        for (int i = 0; i < 16; ++i) {
            int task = i * 256 + tid;
            int c = task >> 4, chunk = task & 15;
            float4 v = *(const float4*)(gx + (size_t)c * TV + chunk * 4);
            int g0 = c >> 3, cl = c & 7;
            #pragma unroll
            for (int k = 0; k < 4; ++k) {
                int j = chunk * 4 + k;
                int f = g0 ^ (j & 7) ^ ((j >> 2) & 7);
                float val = (k == 0) ? v.x : (k == 1) ? v.y : (k == 2) ? v.z : v.w;
                sB[j * 256 + f * 8 + cl] = f2bf(val);
            }
        }
        __syncthreads();
        int quad = lane >> 4, c16 = lane & 15;
        const bshort8* Af = (const bshort8*)w3f;
        f32x4 acc[4][4];
        #pragma unroll
        for (int mt = 0; mt < 4; ++mt)
            #pragma unroll
            for (int nt = 0; nt < 4; ++nt) acc[mt][nt] = (f32x4){0,0,0,0};
        #pragma unroll
        for (int ks = 0; ks < 8; ++ks) {
            bshort8 b[4], a[4];
            #pragma unroll
            for (int nt = 0; nt < 4; ++nt) {
                int rB = nt * 16 + c16;
                int cidx = ks * 4 + quad;
                int f = cidx ^ (rB & 7) ^ ((rB >> 2) & 7);
                b[nt] = *(const bshort8*)(&sB[rB * 256 + f * 8]);
            }
            #pragma unroll
            for (int mt = 0; mt < 4; ++mt)
                a[mt] = Af[(size_t)(((wave * 4 + mt) * 8 + ks) * 64) + lane];
            #pragma unroll
            for (int mt = 0; mt < 4; ++mt)
                #pragma unroll
                for (int nt = 0; nt < 4; ++nt)
                    acc[mt][nt] = __builtin_amdgcn_mfma_f32_16x16x32_bf16(a[mt], b[nt], acc[mt][nt], 0, 0, 0);
        }
        __syncthreads();                      // sB free; alias as epilogue buffer
        unsigned short* eS = sB;              // 128 rows x stride 72 shorts
        #pragma unroll
        for (int pass = 0; pass < 2; ++pass) {
            if ((wave >> 1) == pass) {
                #pragma unroll
                for (int mt = 0; mt < 4; ++mt) {
                    int o = wave * 64 + mt * 16 + quad * 4;
                    float4 bvv = *(const float4*)(b3 + o);
                    int ol = (wave & 1) * 64 + mt * 16 + quad * 4;
                    #pragma unroll
                    for (int nt = 0; nt < 4; ++nt) {
                        int jc = nt * 16 + c16;
                        eS[(ol + 0) * 72 + jc] = f2bf(acc[mt][nt][0] + bvv.x);
                        eS[(ol + 1) * 72 + jc] = f2bf(acc[mt][nt][1] + bvv.y);
                        eS[(ol + 2) * 72 + jc] = f2bf(acc[mt][nt][2] + bvv.z);
                        eS[(ol + 3) * 72 + jc] = f2bf(acc[mt][nt][3] + bvv.w);
                    }
                }
            }
            __syncthreads();
            #pragma unroll
            for (int i = 0; i < 4; ++i) {
                int task = i * 256 + tid;         // 1024
                int orow = task >> 3, seg = task & 7;
                bshort8 vv = *(const bshort8*)&eS[orow * 72 + seg * 8];
                *(bshort8*)(x3 + (size_t)(n * CO + pass * 128 + orow) * TV + j0 + seg * 8) = vv;
            }
            __syncthreads();
        }
    } else {
        // ---------------- attn path ----------------
        float* s_x1 = (float*)smem;               // 800
        float* s_x2 = s_x1 + CR * V_;             // 800
        float* s_A  = s_x2 + CR * V_;             // 625
        int b2 = bb - 1600;
        int n = b2 >> 3, by = b2 & 7;
        float alpha = (float)alpha_p[0];
        for (int i = tid; i < CR * V_; i += 256) {
            s_x1[i] = x1[n * CR * V_ + i];
            s_x2[i] = x2[n * CR * V_ + i];
        }
        for (int i = tid; i < VV; i += 256) s_A[i] = A[i];
        __syncthreads();
        int wave = tid >> 6, lane = tid & 63;
        int task = by * 4 + wave;               // 0..31
        int og   = task & 3;
        int ug   = task >> 2;
        int o0   = og * 64;
        int quad = lane >> 4, c16 = lane & 15;
        bshort8 a[4];
        #pragma unroll
        for (int ot = 0; ot < 4; ++ot)
            a[ot] = *(const bshort8*)(w4f + (size_t)(((og * 4) + ot) * 64 + lane) * 8);
        float4 bv[4];
        #pragma unroll
        for (int ot = 0; ot < 4; ++ot)
            bv[ot] = *(const float4*)(b4 + o0 + ot * 16 + quad * 4);
        int r0 = quad * 8;
        #pragma unroll
        for (int it = 0; it < 5; ++it) {
            int uv0 = (ug * 5 + it) * 16;
            int uvc = uv0 + c16;
            bool valid = uvc < VV;
            int uvcc = valid ? uvc : (VV - 1);
            int u = uvcc % V_, v = uvcc / V_;
            bshort8 b;
            #pragma unroll
            for (int i = 0; i < 8; ++i) {
                float d = s_x1[(r0 + i) * V_ + u] - s_x2[(r0 + i) * V_ + v];
                b[i] = (short)f2bf(tanhf(d));
            }
            float Auv = s_A[u * V_ + v];
            f32x4 acc[4];
            #pragma unroll
            for (int ot = 0; ot < 4; ++ot)
                acc[ot] = __builtin_amdgcn_mfma_f32_16x16x32_bf16(a[ot], b, (f32x4){0,0,0,0}, 0, 0, 0);
            if (valid) {
                #pragma unroll
                for (int ot = 0; ot < 4; ++ot) {
                    #pragma unroll
                    for (int r = 0; r < 4; ++r) {
                        int o = o0 + ot * 16 + quad * 4 + r;
                        float bval = (r == 0) ? bv[ot].x : (r == 1) ? bv[ot].y
                                   : (r == 2) ? bv[ot].z : bv[ot].w;
                        attnT[(size_t)(n * CO + o) * ATS + uvc] =
                            f2bf((acc[ot][r] + bval) * alpha + Auv);
                    }
                }
            }
        }
    }
}

// ---------------- K5: MFMA contraction: out[t,v] = sum_u x3[t,u] * attnT[v,u] ----------------
// block = 4 (n,o) pairs, one wave each. A-frags gathered DIRECTLY from global x3
// (u-contiguous per frag; u>=25 lanes masked to 0). Only attnT staged to LDS (8KB).
__global__ __launch_bounds__(256) void k_contract(const unsigned short* __restrict__ x3,
                                                  const unsigned short* __restrict__ attnT,
                                                  float* __restrict__ out) {
    int no0 = blockIdx.x * 4;
    __shared__ __align__(16) unsigned short sB[4 * 1024];   // 4 x [32 v][32 u]
    int tid = threadIdx.x;
    int p = tid >> 6, lane = tid & 63;
    int quad = lane >> 4, c16 = lane & 15;
    const unsigned short* pAg = x3 + (size_t)(no0 + p) * TV;
    bshort8 a[4];
    #pragma unroll
    for (int mt = 0; mt < 4; ++mt) {
        int t = mt * 16 + c16;
        const unsigned short* rowp = pAg + t * 25 + quad * 8;
        bshort8 av;
        #pragma unroll
        for (int i = 0; i < 8; ++i) {
            unsigned short val = rowp[i];
            av[i] = (short)((quad * 8 + i < 25) ? val : (unsigned short)0);
        }
        a[mt] = av;
    }
    {
        int task = tid;                         // 4*25*7 = 700
        for (int i = 0; i < 3; ++i, task += 256)
            if (task < 700) {
                int pp = task / 175, rem = task % 175;
                sB[pp * 1024 + (rem / 7) * 32 + 25 + rem % 7] = 0;
            }
    }
    #pragma unroll
    for (int i = 0; i < 2; ++i) {
        int task = i * 256 + tid;              // 4*79 = 316
        if (task < 316) {
            int pp = task / 79, e8 = task % 79;
            bshort8 vv = *(const bshort8*)(attnT + (size_t)(no0 + pp) * ATS + e8 * 8);
            #pragma unroll
            for (int k = 0; k < 8; ++k) {
                int idx = e8 * 8 + k;
                if (idx < VV) {
                    int v = idx / 25, u = idx % 25;
                    sB[pp * 1024 + v * 32 + u] = (unsigned short)vv[k];
                }
            }
        }
    }
    __syncthreads();
    const unsigned short* pB = sB + p * 1024;
    bshort8 b[2];
    #pragma unroll
    for (int nt = 0; nt < 2; ++nt) b[nt] = *(const bshort8*)&pB[(nt * 16 + c16) * 32 + quad * 8];
    f32x4 acc[4][2];
    #pragma unroll
    for (int mt = 0; mt < 4; ++mt)
        #pragma unroll
        for (int nt = 0; nt < 2; ++nt)
            acc[mt][nt] = __builtin_amdgcn_mfma_f32_16x16x32_bf16(a[mt], b[nt], (f32x4){0,0,0,0}, 0, 0, 0);
    size_t ob = (size_t)(no0 + p) * TV;
    #pragma unroll
    for (int mt = 0; mt < 4; ++mt)
        #pragma unroll
        for (int nt = 0; nt < 2; ++nt) {
            int v = nt * 16 + c16;
            if (v < V_) {
                #pragma unroll
                for (int r = 0; r < 4; ++r) {
                    int t = mt * 16 + quad * 4 + r;
                    out[ob + t * 25 + v] = acc[mt][nt][r];
                }
            }
        }
}

extern "C" void kernel_launch(void* const* d_in, const int* in_sizes, int n_in,
                              void* d_out, int out_size, void* d_ws, size_t ws_size,
                              hipStream_t stream) {
    const float* x  = (const float*)d_in[0];
    const float* A  = (const float*)d_in[1];
    const float* w1 = (const float*)d_in[2];
    const float* b1 = (const float*)d_in[3];
    const float* w2 = (const float*)d_in[4];
    const float* b2 = (const float*)d_in[5];
    const float* w3 = (const float*)d_in[6];
    const float* b3 = (const float*)d_in[7];
    const float* w4 = (const float*)d_in[8];
    const float* b4 = (const float*)d_in[9];
    const int* alpha_p = (const int*)d_in[11];
    float* out = (float*)d_out;

    float* ws = (float*)d_ws;
    float* xm = ws;                                            // 409600 f
    float* x1 = ws + 409600;                                   // 51200 f
    float* x2 = ws + 460800;                                   // 51200 f
    unsigned short* attnT = (unsigned short*)(ws + 512000);    // 16384*640 us
    unsigned short* w3f   = attnT + (size_t)16384 * ATS;       // 65536 us
    unsigned short* w4f   = w3f + 65536;                       // 16384 us
    unsigned short* x3    = w4f + 16384;                       // 26214400 us

    k_mean_cvt<<<1060, 256, 0, stream>>>(x, w3, w4, xm, w3f, w4f);
    k_x1x2<<<dim3(N_, 4), 256, 0, stream>>>(xm, w1, b1, w2, b2, x1, x2);
    k_attn_gemm<<<2112, 256, 0, stream>>>(x, w3f, b3, x3, x1, x2, w4f, b4, A, alpha_p, attnT);
    k_contract<<<4096, 256, 0, stream>>>(x3, attnT, out);
}